// Round 1
// baseline (2059.778 us; speedup 1.0000x reference)
//
#include <hip/hip_runtime.h>
#include <math.h>

// Problem constants (fixed by reference file)
#define NN   100000   // nodes
#define NE   640000   // edges
#define DIN  128      // in_channels
#define DO   128      // out_channels (H*C)
#define ED   256      // edge dim (MSG + TD)
#define MSGD 128
#define TDD  128

// Workspace layout (floats):
//   Q    [NN*128]
//   K    [NN*128]
//   V    [NN*128]
//   VE   [NE*128]   (v[src] + e per edge)
//   EA   [NE*2]     (exp(alpha) per edge/head)
//   DEN  [NN*2]     (softmax denominators)
// total ~487 MB

__device__ __forceinline__ float fast_cos(float x) {
    // cos(x) via hw v_cos_f32 (argument in revolutions) with explicit range
    // reduction; arg error ~= f32 quantization of x itself (x up to ~4e3).
    float rev = x * 0.15915494309189535f;  // 1/(2*pi)
    rev = rev - rintf(rev);                // [-0.5, 0.5]
    return __builtin_amdgcn_cosf(rev);
}

// ---------------------------------------------------------------------------
// Kernel 1: node projections. 32 nodes per block, 256 threads.
// Computes Q,K,V into ws and out = x@W_skip + b_skip into d_out.
// ---------------------------------------------------------------------------
__global__ __launch_bounds__(256) void node_proj_kernel(
    const float* __restrict__ x,
    const float* __restrict__ Wq, const float* __restrict__ bq,
    const float* __restrict__ Wk, const float* __restrict__ bk,
    const float* __restrict__ Wv, const float* __restrict__ bv,
    const float* __restrict__ Ws, const float* __restrict__ bs,
    float* __restrict__ Q, float* __restrict__ K, float* __restrict__ V,
    float* __restrict__ out)
{
    __shared__ float xt[DIN][36];  // x tile transposed [r][node], pad 32->36 (16B-aligned rows)
    const int tid = threadIdx.x;
    const int n0 = blockIdx.x * 32;

    // stage x tile (coalesced reads)
    #pragma unroll
    for (int i = 0; i < 16; ++i) {
        int v = i * 256 + tid;       // v = n*128 + r
        int n = v >> 7, r = v & 127;
        xt[r][n] = x[(size_t)(n0 + n) * DIN + r];
    }
    __syncthreads();

    const int c = tid & 127;         // output column
    const int g = tid >> 7;          // node group: 0 -> nodes 0..15, 1 -> 16..31
    const float* Wm[4] = {Wq, Wk, Wv, Ws};
    const float* Bm[4] = {bq, bk, bv, bs};
    float*       Om[4] = {Q, K, V, out};

    for (int m = 0; m < 4; ++m) {
        const float* __restrict__ W = Wm[m];
        float bias = Bm[m][c];
        float acc[16];
        #pragma unroll
        for (int i = 0; i < 16; ++i) acc[i] = bias;
        #pragma unroll 4
        for (int r = 0; r < DIN; ++r) {
            float w = W[r * DO + c];   // coalesced, L2-hot (64KB/matrix)
            const float4* xr = (const float4*)(&xt[r][g * 16]);  // LDS broadcast
            #pragma unroll
            for (int j = 0; j < 4; ++j) {
                float4 a = xr[j];
                acc[4*j+0] += a.x * w;
                acc[4*j+1] += a.y * w;
                acc[4*j+2] += a.z * w;
                acc[4*j+3] += a.w * w;
            }
        }
        float* __restrict__ O = Om[m];
        #pragma unroll
        for (int i = 0; i < 16; ++i)
            O[(size_t)(n0 + g * 16 + i) * DO + c] = acc[i];
    }
}

// ---------------------------------------------------------------------------
// Kernel 2: per-edge. 32 edges per block, 256 threads.
// attr = [msg | cos(rel_t*w_time+b_time)] staged transposed in LDS.
// e = attr @ W_e;  alpha = q[dst]·(k[src]+e)/8 (wave-reduce, wave==head);
// ea = exp(alpha) (no segment-max: |alpha| is small, mathematically identical);
// VE = v[src]+e stored; denom[dst][h] += ea (atomic).
// ---------------------------------------------------------------------------
__global__ __launch_bounds__(256) void edge_kernel(
    const float* __restrict__ last_update, const float* __restrict__ tarr,
    const float* __restrict__ msg,
    const float* __restrict__ w_time, const float* __restrict__ b_time,
    const float* __restrict__ We,
    const int* __restrict__ srcI, const int* __restrict__ dstI,
    const float* __restrict__ Q, const float* __restrict__ K,
    const float* __restrict__ V,
    float* __restrict__ VE, float* __restrict__ EA, float* __restrict__ DEN)
{
    __shared__ float at[ED][36];     // attr transposed [r][edge], 36 KB
    __shared__ int ssrc[32], sdst[32];
    const int tid = threadIdx.x;
    const int e0 = blockIdx.x * 32;

    if (tid < 32) {
        ssrc[tid] = srcI[e0 + tid];
        sdst[tid] = dstI[e0 + tid];
    }
    __syncthreads();

    // stage attr: iteration e -> thread tid covers row r=tid of edge e
    for (int e = 0; e < 32; ++e) {
        int r = tid;
        if (r < MSGD) {
            at[r][e] = msg[(size_t)(e0 + e) * MSGD + r];
        } else {
            int j = r - MSGD;
            float rel = last_update[ssrc[e]] - tarr[e0 + e];
            at[r][e] = fast_cos(rel * w_time[j] + b_time[j]);
        }
    }
    __syncthreads();

    const int c  = tid & 127;        // output column
    const int g  = tid >> 7;         // edge group: 0 -> edges 0..15, 1 -> 16..31
    const int eb = g * 16;

    float acc[16];
    #pragma unroll
    for (int i = 0; i < 16; ++i) acc[i] = 0.f;

    #pragma unroll 4
    for (int r = 0; r < ED; ++r) {
        float w = We[r * DO + c];    // coalesced, L2-hot (128KB matrix)
        const float4* ar = (const float4*)(&at[r][eb]);  // LDS broadcast
        #pragma unroll
        for (int j = 0; j < 4; ++j) {
            float4 a = ar[j];
            acc[4*j+0] += a.x * w;
            acc[4*j+1] += a.y * w;
            acc[4*j+2] += a.z * w;
            acc[4*j+3] += a.w * w;
        }
    }

    const int h    = c >> 6;         // head (wave 0/2 -> h0, wave 1/3 -> h1)
    const int lane = tid & 63;

    for (int i = 0; i < 16; ++i) {
        int e = e0 + eb + i;
        int s = ssrc[eb + i], d = sdst[eb + i];
        float ev = acc[i];
        float qv = Q[(size_t)d * DO + c];
        float kv = K[(size_t)s * DO + c];
        float vv = V[(size_t)s * DO + c];
        VE[(size_t)e * DO + c] = vv + ev;
        float p = qv * (kv + ev);
        #pragma unroll
        for (int off = 32; off; off >>= 1) p += __shfl_xor(p, off, 64);
        if (lane == 0) {
            float ea = __expf(p * 0.125f);   // / sqrt(C=64)
            EA[(size_t)e * 2 + h] = ea;
            atomicAdd(&DEN[(size_t)d * 2 + h], ea);
        }
    }
}

// ---------------------------------------------------------------------------
// Kernel 3: scatter output. one thread per (edge, col).
// ---------------------------------------------------------------------------
__global__ __launch_bounds__(256) void scatter_kernel(
    const int* __restrict__ dstI,
    const float* __restrict__ VE, const float* __restrict__ EA,
    const float* __restrict__ DEN, float* __restrict__ out)
{
    size_t v = (size_t)blockIdx.x * 256 + threadIdx.x;
    int e = (int)(v >> 7);
    int c = (int)(v & 127);
    int d = dstI[e];
    int h = c >> 6;
    float ea  = EA[(size_t)e * 2 + h];
    float den = DEN[(size_t)d * 2 + h];
    float attn = ea / (den + 1e-16f);
    atomicAdd(&out[(size_t)d * DO + c], VE[v] * attn);
}

extern "C" void kernel_launch(void* const* d_in, const int* in_sizes, int n_in,
                              void* d_out, int out_size, void* d_ws, size_t ws_size,
                              hipStream_t stream) {
    const float* x           = (const float*)d_in[0];
    const float* last_update = (const float*)d_in[1];
    const float* tarr        = (const float*)d_in[2];
    const float* msg         = (const float*)d_in[3];
    const float* w_time      = (const float*)d_in[4];
    const float* b_time      = (const float*)d_in[5];
    const float* Wq          = (const float*)d_in[6];
    const float* bq          = (const float*)d_in[7];
    const float* Wk          = (const float*)d_in[8];
    const float* bk          = (const float*)d_in[9];
    const float* Wv          = (const float*)d_in[10];
    const float* bv          = (const float*)d_in[11];
    const float* We          = (const float*)d_in[12];
    const float* Ws          = (const float*)d_in[13];
    const float* bs          = (const float*)d_in[14];
    const int*   ei          = (const int*)d_in[15];
    const int*   srcI = ei;
    const int*   dstI = ei + NE;

    float* out = (float*)d_out;
    float* ws  = (float*)d_ws;
    float* Q   = ws;
    float* K   = Q  + (size_t)NN * DO;
    float* V   = K  + (size_t)NN * DO;
    float* VE  = V  + (size_t)NN * DO;
    float* EA  = VE + (size_t)NE * DO;
    float* DEN = EA + (size_t)NE * 2;

    hipMemsetAsync(DEN, 0, (size_t)NN * 2 * sizeof(float), stream);

    node_proj_kernel<<<NN / 32, 256, 0, stream>>>(
        x, Wq, bq, Wk, bk, Wv, bv, Ws, bs, Q, K, V, out);

    edge_kernel<<<NE / 32, 256, 0, stream>>>(
        last_update, tarr, msg, w_time, b_time, We, srcI, dstI,
        Q, K, V, VE, EA, DEN);

    scatter_kernel<<<(NE * (size_t)DO) / 256, 256, 0, stream>>>(
        dstI, VE, EA, DEN, out);
}

// Round 2
// 1178.945 us; speedup vs baseline: 1.7471x; 1.7471x over previous
//
#include <hip/hip_runtime.h>
#include <hip/hip_bf16.h>
#include <math.h>

// Problem constants (fixed by reference file)
#define NN   100000   // nodes
#define NE   640000   // edges
#define DIN  128      // in_channels
#define DO   128      // out_channels (H*C)
#define ED   256      // edge dim (MSG + TD)
#define MSGD 128

typedef __attribute__((ext_vector_type(8))) short s16x8;           // 8 bf16 (A/B frag)
typedef __attribute__((ext_vector_type(4))) float f32x4;           // C/D frag
typedef __attribute__((ext_vector_type(4))) unsigned short u16x4;
typedef __attribute__((ext_vector_type(8))) unsigned short u16x8;

__device__ __forceinline__ unsigned short f2bs(float f) {
    __hip_bfloat16 h = __float2bfloat16(f);   // RNE
    return __builtin_bit_cast(unsigned short, h);
}
__device__ __forceinline__ float bs2f(unsigned short u) {
    return __uint_as_float(((unsigned int)u) << 16);
}
__device__ __forceinline__ float fast_cos(float x) {
    float rev = x * 0.15915494309189535f;   // 1/(2pi)
    rev = rev - rintf(rev);                 // revolutions, range-reduced
    return __builtin_amdgcn_cosf(rev);
}

// ---------------------------------------------------------------------------
// Kernel 0: dtype conversion + weight transposes (tiny).
// xb = bf16(x); WT[n][k] = bf16(W[k][n]) for We, Wq, Wk, Wv, Wskip.
// ---------------------------------------------------------------------------
__global__ __launch_bounds__(256) void convert_kernel(
    const float* __restrict__ x, const float* __restrict__ We,
    const float* __restrict__ Wq, const float* __restrict__ Wk,
    const float* __restrict__ Wv, const float* __restrict__ Ws,
    unsigned short* __restrict__ xb, unsigned short* __restrict__ WeT,
    unsigned short* __restrict__ WqT, unsigned short* __restrict__ WkT,
    unsigned short* __restrict__ WvT, unsigned short* __restrict__ WsT)
{
    const size_t XTOT = (size_t)NN * DIN;          // 12.8M
    const size_t T1   = XTOT + ED * DO;            // + WeT (32768)
    const size_t TOT  = T1 + 4 * DIN * DO;         // + 4 node mats
    size_t i = (size_t)blockIdx.x * 256 + threadIdx.x;
    if (i >= TOT) return;
    if (i < XTOT) {
        xb[i] = f2bs(x[i]);
    } else if (i < T1) {
        int j = (int)(i - XTOT); int n = j >> 8, k = j & 255;
        WeT[j] = f2bs(We[(size_t)k * DO + n]);
    } else {
        int j = (int)(i - T1); int m = j >> 14; int r = j & 16383;
        int n = r >> 7, k = r & 127;
        const float* W = (m == 0) ? Wq : (m == 1) ? Wk : (m == 2) ? Wv : Ws;
        unsigned short* WD = (m == 0) ? WqT : (m == 1) ? WkT : (m == 2) ? WvT : WsT;
        WD[r] = f2bs(W[(size_t)k * DO + n]);
    }
}

// ---------------------------------------------------------------------------
// Kernel 1: node projections via MFMA. 64 nodes/block, 256 threads (4 waves).
// Q,K,V stored bf16 (halves edge-gather traffic); SKIP stored fp32.
// ---------------------------------------------------------------------------
__global__ __launch_bounds__(256) void node_proj_kernel(
    const unsigned short* __restrict__ xb,
    const unsigned short* __restrict__ WqT, const float* __restrict__ bq,
    const unsigned short* __restrict__ WkT, const float* __restrict__ bk,
    const unsigned short* __restrict__ WvT, const float* __restrict__ bv,
    const unsigned short* __restrict__ WsT, const float* __restrict__ bs,
    unsigned short* __restrict__ Qb, unsigned short* __restrict__ Kb,
    unsigned short* __restrict__ Vb, float* __restrict__ SKIP)
{
    __shared__ unsigned short xt[64 * 136];   // 64 nodes x 128k, pad +8 (rows 272B, 16B-aligned)
    const int tid = threadIdx.x;
    const int n0  = blockIdx.x * 64;

    #pragma unroll
    for (int i = 0; i < 4; ++i) {             // 1024 x 16B chunks / 256 thr
        int q = i * 256 + tid; int row = q >> 4, ch = q & 15;
        int gn = n0 + row; if (gn > NN - 1) gn = NN - 1;
        u16x8 v = *(const u16x8*)(xb + (size_t)gn * DIN + ch * 8);
        *(u16x8*)(xt + row * 136 + ch * 8) = v;
    }
    __syncthreads();

    const int lane = tid & 63, w = tid >> 6;
    const int l15 = lane & 15, quad = lane >> 4;
    const unsigned short* arow = xt + (w * 16 + l15) * 136 + quad * 8;

    const unsigned short* WT[4] = {WqT, WkT, WvT, WsT};
    const float*          BI[4] = {bq, bk, bv, bs};

    #pragma unroll
    for (int m = 0; m < 4; ++m) {
        f32x4 acc[8];
        #pragma unroll
        for (int j = 0; j < 8; ++j) { float b = BI[m][j * 16 + l15]; acc[j] = {b, b, b, b}; }
        const unsigned short* Wm = WT[m];
        #pragma unroll
        for (int ks = 0; ks < 4; ++ks) {
            s16x8 a = *(const s16x8*)(arow + ks * 32);
            #pragma unroll
            for (int j = 0; j < 8; ++j) {
                s16x8 bf = *(const s16x8*)(Wm + (j * 16 + l15) * DIN + ks * 32 + quad * 8);
                acc[j] = __builtin_amdgcn_mfma_f32_16x16x32_bf16(a, bf, acc[j], 0, 0, 0);
            }
        }
        #pragma unroll
        for (int j = 0; j < 8; ++j) {
            int col = j * 16 + l15;
            #pragma unroll
            for (int r = 0; r < 4; ++r) {
                int node = n0 + w * 16 + quad * 4 + r;
                if (node < NN) {
                    float v = acc[j][r];
                    if (m == 0)      Qb[(size_t)node * DO + col] = f2bs(v);
                    else if (m == 1) Kb[(size_t)node * DO + col] = f2bs(v);
                    else if (m == 2) Vb[(size_t)node * DO + col] = f2bs(v);
                    else             SKIP[(size_t)node * DO + col] = v;
                }
            }
        }
    }
}

// ---------------------------------------------------------------------------
// Kernel 2: edge kernel. 64 edges/block, 256 threads (4 waves).
// attr (bf16) staged in LDS -> e = attr @ We via MFMA -> e tiles written back
// into the SAME LDS buffer (fp32) -> per-edge alpha / exp / atomic NUM,DEN.
// No segment-max: |alpha| <~ 12, exp safe in fp32, result identical.
// ---------------------------------------------------------------------------
__global__ __launch_bounds__(256) void edge_kernel(
    const float* __restrict__ last_update, const float* __restrict__ tarr,
    const float* __restrict__ msg,
    const float* __restrict__ w_time, const float* __restrict__ b_time,
    const unsigned short* __restrict__ WeT,
    const int* __restrict__ srcI, const int* __restrict__ dstI,
    const unsigned short* __restrict__ Qb, const unsigned short* __restrict__ Kb,
    const unsigned short* __restrict__ Vb,
    float* __restrict__ NUM, float* __restrict__ DEN)
{
    // 64 rows x 528B: as bf16 attr rows (264 elems, 256 + 8 pad),
    // then reused as fp32 e rows (132 elems, 128 + 4 pad).
    __shared__ char smem[64 * 528];
    __shared__ int   ssrc[64], sdst[64];
    __shared__ float srel[64];
    const int tid = threadIdx.x;
    const int e0  = blockIdx.x * 64;

    if (tid < 64) {
        int s = srcI[e0 + tid], d = dstI[e0 + tid];
        ssrc[tid] = s; sdst[tid] = d;
        srel[tid] = last_update[s] - tarr[e0 + tid];
    }
    __syncthreads();

    unsigned short* at = (unsigned short*)smem;
    // stage msg -> bf16 (coalesced float4 reads)
    const float4* msg4 = (const float4*)msg;
    #pragma unroll
    for (int i = 0; i < 8; ++i) {
        int q = i * 256 + tid; int e = q >> 5, c4 = q & 31;
        float4 m4 = msg4[(size_t)(e0 + e) * 32 + c4];
        u16x4 b; b.x = f2bs(m4.x); b.y = f2bs(m4.y); b.z = f2bs(m4.z); b.w = f2bs(m4.w);
        *(u16x4*)(at + e * 264 + c4 * 4) = b;
    }
    // stage time encoding -> bf16
    #pragma unroll
    for (int i = 0; i < 32; ++i) {
        int q = i * 256 + tid; int e = q >> 7, j = q & 127;
        float v = fast_cos(srel[e] * w_time[j] + b_time[j]);
        at[e * 264 + MSGD + j] = f2bs(v);
    }
    __syncthreads();

    const int lane = tid & 63, w = tid >> 6;
    const int l15 = lane & 15, quad = lane >> 4;

    // MFMA: wave w computes edges w*16..w*16+15 x all 128 cols
    f32x4 acc[8];
    #pragma unroll
    for (int j = 0; j < 8; ++j) acc[j] = {0.f, 0.f, 0.f, 0.f};
    const unsigned short* arow = at + (w * 16 + l15) * 264 + quad * 8;
    #pragma unroll
    for (int ks = 0; ks < 8; ++ks) {
        s16x8 a = *(const s16x8*)(arow + ks * 32);
        #pragma unroll
        for (int j = 0; j < 8; ++j) {
            s16x8 b = *(const s16x8*)(WeT + (j * 16 + l15) * ED + ks * 32 + quad * 8);
            acc[j] = __builtin_amdgcn_mfma_f32_16x16x32_bf16(a, b, acc[j], 0, 0, 0);
        }
    }
    __syncthreads();   // attr fully consumed; reuse buffer for e (fp32)

    float* eld = (float*)smem;
    #pragma unroll
    for (int j = 0; j < 8; ++j) {
        #pragma unroll
        for (int r = 0; r < 4; ++r)
            eld[(w * 16 + quad * 4 + r) * 132 + j * 16 + l15] = acc[j][r];
    }
    __syncthreads();

    // per-edge: alpha = q[dst]·(k[src]+e)/8, ea = exp, atomic NUM/DEN
    const int c = tid & 127;          // wave0: head0 cols, wave1: head1 cols
    const int g = tid >> 7;           // edge half
    const int h = c >> 6;
    #pragma unroll 4
    for (int i = 0; i < 32; ++i) {
        int e = g * 32 + i;
        int s = ssrc[e], d = sdst[e];
        float ev = eld[e * 132 + c];
        float qv = bs2f(Qb[(size_t)d * DO + c]);
        float kv = bs2f(Kb[(size_t)s * DO + c]);
        float vv = bs2f(Vb[(size_t)s * DO + c]);
        float p = qv * (kv + ev);
        #pragma unroll
        for (int off = 32; off; off >>= 1) p += __shfl_xor(p, off, 64);
        float ea = __expf(p * 0.125f);                 // / sqrt(C=64)
        atomicAdd(&NUM[(size_t)d * DO + c], ea * (vv + ev));
        if (lane == 0) atomicAdd(&DEN[d * 2 + h], ea);
    }
}

// ---------------------------------------------------------------------------
// Kernel 3: out = NUM / (DEN + 1e-16) + SKIP  (vectorized float4)
// ---------------------------------------------------------------------------
__global__ __launch_bounds__(256) void final_kernel(
    const float* __restrict__ NUM, const float* __restrict__ DEN,
    const float* __restrict__ SKIP, float* __restrict__ out)
{
    size_t i4 = (size_t)blockIdx.x * 256 + threadIdx.x;
    size_t base = i4 * 4;
    int node = (int)(base >> 7);
    int h = (int)((base & 127) >> 6);
    float inv = 1.0f / (DEN[node * 2 + h] + 1e-16f);
    float4 nv = ((const float4*)NUM)[i4];
    float4 sv = ((const float4*)SKIP)[i4];
    float4 o;
    o.x = nv.x * inv + sv.x;
    o.y = nv.y * inv + sv.y;
    o.z = nv.z * inv + sv.z;
    o.w = nv.w * inv + sv.w;
    ((float4*)out)[i4] = o;
}

extern "C" void kernel_launch(void* const* d_in, const int* in_sizes, int n_in,
                              void* d_out, int out_size, void* d_ws, size_t ws_size,
                              hipStream_t stream) {
    const float* x           = (const float*)d_in[0];
    const float* last_update = (const float*)d_in[1];
    const float* tarr        = (const float*)d_in[2];
    const float* msg         = (const float*)d_in[3];
    const float* w_time      = (const float*)d_in[4];
    const float* b_time      = (const float*)d_in[5];
    const float* Wq          = (const float*)d_in[6];
    const float* bq          = (const float*)d_in[7];
    const float* Wk          = (const float*)d_in[8];
    const float* bk          = (const float*)d_in[9];
    const float* Wv          = (const float*)d_in[10];
    const float* bv          = (const float*)d_in[11];
    const float* We          = (const float*)d_in[12];
    const float* Ws          = (const float*)d_in[13];
    const float* bs          = (const float*)d_in[14];
    const int*   ei          = (const int*)d_in[15];
    const int*   srcI = ei;
    const int*   dstI = ei + NE;

    float* out = (float*)d_out;
    char*  ws  = (char*)d_ws;
    // byte layout (all 16B-aligned)
    unsigned short* xb  = (unsigned short*)(ws);                    // 25,600,000
    unsigned short* Qb  = (unsigned short*)(ws + 25600000);         // 25,600,000
    unsigned short* Kb  = (unsigned short*)(ws + 51200000);         // 25,600,000
    unsigned short* Vb  = (unsigned short*)(ws + 76800000);         // 25,600,000
    unsigned short* WeT = (unsigned short*)(ws + 102400000);        // 65,536
    unsigned short* WqT = (unsigned short*)(ws + 102465536);        // 32,768
    unsigned short* WkT = (unsigned short*)(ws + 102498304);        // 32,768
    unsigned short* WvT = (unsigned short*)(ws + 102531072);        // 32,768
    unsigned short* WsT = (unsigned short*)(ws + 102563840);        // 32,768
    float*          SKIP= (float*)(ws + 102596608);                 // 51,200,000
    float*          NUM = (float*)(ws + 153796608);                 // 51,200,000
    float*          DEN = (float*)(ws + 204996608);                 // 800,000

    hipMemsetAsync(NUM, 0, (size_t)NN * DO * sizeof(float), stream);
    hipMemsetAsync(DEN, 0, (size_t)NN * 2 * sizeof(float), stream);

    const size_t TOT = (size_t)NN * DIN + ED * DO + 4 * DIN * DO;
    convert_kernel<<<(unsigned)((TOT + 255) / 256), 256, 0, stream>>>(
        x, We, Wq, Wk, Wv, Ws, xb, WeT, WqT, WkT, WvT, WsT);

    node_proj_kernel<<<(NN + 63) / 64, 256, 0, stream>>>(
        xb, WqT, bq, WkT, bk, WvT, bv, WsT, bs, Qb, Kb, Vb, SKIP);

    edge_kernel<<<NE / 64, 256, 0, stream>>>(
        last_update, tarr, msg, w_time, b_time, WeT, srcI, dstI,
        Qb, Kb, Vb, NUM, DEN);

    final_kernel<<<(NN * (size_t)DO) / 1024, 256, 0, stream>>>(NUM, DEN, SKIP, out);
}